// Round 9
// baseline (369.880 us; speedup 1.0000x reference)
//
#include <hip/hip_runtime.h>
#include <hip/hip_bf16.h>
#include <math.h>

// ---------------------------------------------------------------------------
// Gated causal attention block, bf16 MFMA pipeline. B=2,N=2048,DIM=2048,H=16,DH=128.
// R9: attention occupancy rework -- latency-bound at 18.5% occ (2 blocks/CU,
//     64KB dbuf LDS). Now: one q-tile per block (1024 blocks, heavy-first),
//     single-buffered 32KB KV tile, 4 blocks/CU (launch_bounds(256,4)),
//     barrier/stage/vmcnt(0)/barrier per tile -- TLP across 4 blocks hides
//     latency (m114). Softcap math byte-identical. GEMMs unchanged from R8.
// ---------------------------------------------------------------------------

typedef __attribute__((ext_vector_type(8))) __bf16 bf16x8;
typedef __attribute__((ext_vector_type(4))) __bf16 bf16x4;
typedef __attribute__((ext_vector_type(4))) float f32x4;

#define MFMA_BF16(a, b, c) __builtin_amdgcn_mfma_f32_16x16x32_bf16((a), (b), (c), 0, 0, 0)

#define NB 2
#define NSEQ 2048
#define NDIM 2048
#define NH 16
#define NDH 128
#define SCALE_Q 0.08838834764831845f /* 128^-0.5 */

#define AS1 __attribute__((address_space(1)))
#define AS3 __attribute__((address_space(3)))
static __device__ __forceinline__ void gload_lds16(const void* g, void* l) {
  __builtin_amdgcn_global_load_lds((AS1 const void*)g, (AS3 void*)l, 16, 0, 0);
}

static __device__ __forceinline__ unsigned pack2_bf16(float a, float b) {
  unsigned short ua = __builtin_bit_cast(unsigned short, (__bf16)a);
  unsigned short ub = __builtin_bit_cast(unsigned short, (__bf16)b);
  return (unsigned)ua | ((unsigned)ub << 16);
}

// ---------------------------------------------------------------------------
__global__ __launch_bounds__(256) void cvt_bf16_kernel(const float* __restrict__ in,
                                                       __bf16* __restrict__ out) {
  int i = blockIdx.x * 256 + threadIdx.x;
  float4 v = reinterpret_cast<const float4*>(in)[i];
  bf16x4 o;
  o[0] = (__bf16)v.x; o[1] = (__bf16)v.y; o[2] = (__bf16)v.z; o[3] = (__bf16)v.w;
  reinterpret_cast<bf16x4*>(out)[i] = o;
}

// in: f32 [K][C] row-major -> out: bf16 [C][K] row-major
__global__ __launch_bounds__(256) void transpose_cvt_kernel(const float* __restrict__ in,
                                                            __bf16* __restrict__ out,
                                                            int K, int C) {
  __shared__ float tile[32][33];
  int c0 = blockIdx.x * 32, k0 = blockIdx.y * 32;
  int t = threadIdx.x;
  int lc = t & 31, lr = t >> 5;
#pragma unroll
  for (int rr = 0; rr < 4; ++rr)
    tile[lr + rr * 8][lc] = in[(size_t)(k0 + lr + rr * 8) * C + c0 + lc];
  __syncthreads();
#pragma unroll
  for (int rr = 0; rr < 4; ++rr)
    out[(size_t)(c0 + lr + rr * 8) * K + k0 + lc] = (__bf16)tile[lc][lr + rr * 8];
}

// ---------------------------------------------------------------------------
// qkv core (unchanged R8): BM=256, BN=384, BK=32, 8 waves, LDS ring-of-3.
struct SmemQ {
  __bf16 T[3][640][32];  // 120 KiB
};

static __device__ __forceinline__ const bf16x8* fragq(const __bf16* base, int row, int g) {
  return (const bf16x8*)(base + row * 32 + (g ^ ((row >> 1) & 3)) * 8);
}

__global__ __launch_bounds__(512, 2) void gemm_qkv256b(const __bf16* __restrict__ A,
                                                       const __bf16* __restrict__ Bt,
                                                       __bf16* __restrict__ qb,
                                                       __bf16* __restrict__ kb,
                                                       __bf16* __restrict__ vtb) {
  __shared__ __align__(1024) SmemQ S;
  int sblk = blockIdx.x;
  int x = sblk & 7, i = sblk >> 3;
  int m0 = (i >> 1) * 256;
  int n0 = (2 * x + (i & 1)) * 384;
  const __bf16* Ab = A + (size_t)m0 * 2048;
  const __bf16* Bb = Bt + (size_t)n0 * 2048;

  int tid = threadIdx.x;
  int w = tid >> 6, lane = tid & 63;
  int ln15 = lane & 15, g = lane >> 4;
  int wr = w >> 2, wc = w & 3;
  int lr4 = lane >> 2, l3 = lane & 3;

  auto stage = [&](int kt, int rb) {
#pragma unroll
    for (int j = 0; j < 5; ++j) {
      int k = w + 8 * j;
      int row = k * 16 + lr4;
      int sg = l3 ^ ((row >> 1) & 3);
      const __bf16* src = (k < 16)
          ? Ab + (size_t)row * 2048 + kt * 32 + sg * 8
          : Bb + (size_t)(row - 256) * 2048 + kt * 32 + sg * 8;
      gload_lds16(src, &S.T[rb][k * 16][0]);
    }
  };

  f32x4 acc[8][6];
#pragma unroll
  for (int a = 0; a < 8; ++a)
#pragma unroll
    for (int nf = 0; nf < 6; ++nf) acc[a][nf] = (f32x4){0.f, 0.f, 0.f, 0.f};

  stage(0, 0);
  stage(1, 1);
  for (int t = 0; t < 64; ++t) {
    int rb = t % 3;
    asm volatile("s_waitcnt vmcnt(5)" ::: "memory");
    __builtin_amdgcn_s_barrier();
    asm volatile("" ::: "memory");
    int ts = (t < 62) ? t + 2 : 63;
    stage(ts, (t + 2) % 3);
    const __bf16* Sb = &S.T[rb][0][0];
    bf16x8 bfr[6];
#pragma unroll
    for (int nf = 0; nf < 6; ++nf) {
      int row = 256 + wc * 96 + nf * 16 + ln15;
      bfr[nf] = *fragq(Sb, row, g);
    }
#pragma unroll
    for (int mh = 0; mh < 2; ++mh) {
      bf16x8 af[4];
#pragma unroll
      for (int a = 0; a < 4; ++a) {
        int row = wr * 128 + (mh * 4 + a) * 16 + ln15;
        af[a] = *fragq(Sb, row, g);
      }
      __builtin_amdgcn_s_setprio(1);
#pragma unroll
      for (int a = 0; a < 4; ++a)
#pragma unroll
        for (int nf = 0; nf < 6; ++nf)
          acc[mh * 4 + a][nf] = MFMA_BF16(af[a], bfr[nf], acc[mh * 4 + a][nf]);
      __builtin_amdgcn_s_setprio(0);
    }
  }
  asm volatile("s_waitcnt vmcnt(0)" ::: "memory");

#pragma unroll
  for (int nf = 0; nf < 6; ++nf) {
    int ng = n0 + wc * 96 + nf * 16 + ln15;
    int qkv = ng >> 11;
    int h = (ng >> 7) & 15;
    int d = ng & 127;
#pragma unroll
    for (int mf = 0; mf < 8; ++mf)
#pragma unroll
      for (int rr = 0; rr < 4; ++rr) {
        int m = m0 + wr * 128 + mf * 16 + g * 4 + rr;
        int b = m >> 11, n = m & 2047;
        int bh = b * NH + h;
        float v = acc[mf][nf][rr];
        if (qkv == 0)
          qb[((size_t)bh * NSEQ + n) * NDH + d] = (__bf16)(v * SCALE_Q);
        else if (qkv == 1)
          kb[((size_t)bh * NSEQ + n) * NDH + d] = (__bf16)v;
        else
          vtb[((size_t)bh * NDH + d) * NSEQ + n] = (__bf16)v;
      }
  }
}

// ---------------------------------------------------------------------------
// gemm_out core (unchanged from R7): BM=128 x BN=256, BK=64, 8 waves.
template <int BN> struct SmemG {
  __bf16 A[2][2][128][32];
  __bf16 B[2][2][BN][32];
};

template <int BN>
static __device__ __forceinline__ void stage_half(const __bf16* __restrict__ Ab,
                                                  const __bf16* __restrict__ Bb,
                                                  SmemG<BN>* S, int buf, int ks,
                                                  int kt, int w, int lane) {
  constexpr int LB = BN / 128;
  {
    int gid = w * 64 + lane;
    int row = gid >> 2, gc = gid & 3;
    int sg = gc ^ ((row >> 1) & 3);
    gload_lds16(Ab + (size_t)row * 2048 + kt * 64 + ks * 32 + sg * 8,
                &S->A[buf][ks][0][0] + (size_t)(w * 64) * 8);
  }
#pragma unroll
  for (int j = 0; j < LB; ++j) {
    int gid = j * 512 + w * 64 + lane;
    int row = gid >> 2, gc = gid & 3;
    int sg = gc ^ ((row >> 1) & 3);
    gload_lds16(Bb + (size_t)row * 2048 + kt * 64 + ks * 32 + sg * 8,
                &S->B[buf][ks][0][0] + (size_t)(j * 512 + w * 64) * 8);
  }
}

static __device__ __forceinline__ const bf16x8* fragp(const __bf16* base, int row, int g) {
  return (const bf16x8*)(base + row * 32 + (g ^ ((row >> 1) & 3)) * 8);
}

template <int BN>
static __device__ __forceinline__ void gemm128_core(const __bf16* __restrict__ Abase,
                                                    const __bf16* __restrict__ Bbase,
                                                    SmemG<BN>* S,
                                                    f32x4 (*acc)[BN / 64]) {
  constexpr int NF = BN / 64;
  constexpr int LB = BN / 128;
  int tid = threadIdx.x;
  int w = tid >> 6, lane = tid & 63;
  int ln15 = lane & 15, g = lane >> 4;
  int wr = w >> 2, wc = w & 3;

#pragma unroll
  for (int i = 0; i < 4; ++i)
#pragma unroll
    for (int j = 0; j < NF; ++j) acc[i][j] = (f32x4){0.f, 0.f, 0.f, 0.f};

  stage_half<BN>(Abase, Bbase, S, 0, 0, 0, w, lane);
  stage_half<BN>(Abase, Bbase, S, 0, 1, 0, w, lane);

  for (int t = 0; t < 32; ++t) {
    int bf = t & 1, tb = bf ^ 1;
    int ts = (t < 31) ? t + 1 : 31;
#pragma unroll
    for (int ks = 0; ks < 2; ++ks) {
      stage_half<BN>(Abase, Bbase, S, tb, ks, ts, w, lane);
      if constexpr (LB == 3)
        asm volatile("s_waitcnt vmcnt(8)" ::: "memory");
      else
        asm volatile("s_waitcnt vmcnt(6)" ::: "memory");
      __builtin_amdgcn_s_barrier();
      const __bf16* SA = &S->A[bf][ks][0][0];
      const __bf16* SB = &S->B[bf][ks][0][0];
      bf16x8 af[4], bfr[NF];
#pragma unroll
      for (int nf = 0; nf < NF; ++nf) {
        int row = wc * (BN / 4) + nf * 16 + ln15;
        bfr[nf] = *fragp(SB, row, g);
      }
#pragma unroll
      for (int mf = 0; mf < 4; ++mf) {
        int row = wr * 64 + mf * 16 + ln15;
        af[mf] = *fragp(SA, row, g);
      }
      __builtin_amdgcn_s_setprio(1);
#pragma unroll
      for (int mf = 0; mf < 4; ++mf)
#pragma unroll
        for (int nf = 0; nf < NF; ++nf)
          acc[mf][nf] = MFMA_BF16(af[mf], bfr[nf], acc[mf][nf]);
      __builtin_amdgcn_s_setprio(0);
    }
  }
  asm volatile("s_waitcnt vmcnt(0)" ::: "memory");
}

// Output GEMM: A = attn_g bf16 [4096][2048], Bt = wout_t [2048][2048] -> f32. 256 blocks.
__global__ __launch_bounds__(512) void gemm_out128(const __bf16* __restrict__ A,
                                                   const __bf16* __restrict__ Bt,
                                                   float* __restrict__ out) {
  __shared__ __align__(1024) SmemG<256> S;
  int sblk = blockIdx.x;
  int x = sblk & 7, i = sblk >> 3;
  int m0 = i * 128;
  int n0 = x * 256;
  f32x4 acc[4][4];
  gemm128_core<256>(A + (size_t)m0 * 2048, Bt + (size_t)n0 * 2048, &S, acc);

  int tid = threadIdx.x;
  int w = tid >> 6, lane = tid & 63;
  int ln15 = lane & 15, g = lane >> 4;
  int wr = w >> 2, wc = w & 3;
#pragma unroll
  for (int mf = 0; mf < 4; ++mf)
#pragma unroll
    for (int nf = 0; nf < 4; ++nf)
#pragma unroll
      for (int rr = 0; rr < 4; ++rr) {
        int m = m0 + wr * 64 + mf * 16 + g * 4 + rr;
        int c = n0 + wc * 64 + nf * 16 + ln15;
        out[(size_t)m * NDIM + c] = acc[mf][nf][rr];
      }
}

// ---------------------------------------------------------------------------
// gates[b,h,n] = sigmoid(x[b,n,:] @ w_gates[:,h]) in f32. One block per row.
__global__ __launch_bounds__(256) void gates_kernel(const float* __restrict__ x,
                                                    const float* __restrict__ wg,
                                                    float* __restrict__ gates) {
  __shared__ float red[64];
  int row = blockIdx.x;
  int tid = threadIdx.x;
  float acc[16];
#pragma unroll
  for (int h = 0; h < 16; ++h) acc[h] = 0.f;
  const float* xr = x + (size_t)row * NDIM;
  for (int k = tid; k < NDIM; k += 256) {
    float xv = xr[k];
    const float* wr = wg + (size_t)k * NH;
#pragma unroll
    for (int h = 0; h < 16; ++h) acc[h] += xv * wr[h];
  }
  int w = tid >> 6, lane = tid & 63;
#pragma unroll
  for (int h = 0; h < 16; ++h) {
    float v = acc[h];
#pragma unroll
    for (int off = 32; off; off >>= 1) v += __shfl_down(v, off);
    if (lane == 0) red[w * 16 + h] = v;
  }
  __syncthreads();
  if (tid < 16) {
    float s = red[tid] + red[16 + tid] + red[32 + tid] + red[48 + tid];
    int b = row >> 11, n = row & 2047;
    gates[((size_t)(b * NH + tid)) * NSEQ + n] = 1.f / (1.f + expf(-s));
  }
}

// ---------------------------------------------------------------------------
// Flash attention R9: one q-tile (64 rows) per block, single-buffered 32KB
// KV tile, 4 blocks/CU. Swapped-QK^T, fixed-max softmax (M=12), in-register
// P via pack+shfl. Softcap math byte-identical to R5-R8.
static __device__ __forceinline__ void softcap_p(const f32x4* accS, float (*p)[4],
                                                 float& l_r, int j0, int q0s,
                                                 bool diag, int ln15, int g) {
#pragma unroll
  for (int jt = 0; jt < 4; ++jt)
#pragma unroll
    for (int r = 0; r < 4; ++r) {
      float e2 = __expf(accS[jt][r] * 0.04f);
      float cap = 50.f - __fdividef(100.f, e2 + 1.f);  // 50*tanh(s/50)
      float pv = __expf(cap - 12.f);
      if (diag && (j0 + jt * 16 + g * 4 + r > q0s + ln15)) pv = 0.f;
      p[jt][r] = pv;
      l_r += pv;
    }
}

static __device__ __forceinline__ bf16x8 build_pa(const float (*p)[4], int c,
                                                  int lane_lo, int lane_hi, int g) {
  unsigned P0w0 = pack2_bf16(p[2 * c][0], p[2 * c][1]);
  unsigned P0w1 = pack2_bf16(p[2 * c][2], p[2 * c][3]);
  unsigned P1w0 = pack2_bf16(p[2 * c + 1][0], p[2 * c + 1][1]);
  unsigned P1w1 = pack2_bf16(p[2 * c + 1][2], p[2 * c + 1][3]);
  unsigned a0 = (unsigned)__shfl((int)P0w0, lane_lo);
  unsigned a1 = (unsigned)__shfl((int)P0w1, lane_lo);
  unsigned b0 = (unsigned)__shfl((int)P1w0, lane_lo);
  unsigned b1 = (unsigned)__shfl((int)P1w1, lane_lo);
  unsigned c0 = (unsigned)__shfl((int)P0w0, lane_hi);
  unsigned c1 = (unsigned)__shfl((int)P0w1, lane_hi);
  unsigned e0 = (unsigned)__shfl((int)P1w0, lane_hi);
  unsigned e1 = (unsigned)__shfl((int)P1w1, lane_hi);
  union { unsigned u[4]; bf16x8 v; } pu;
  pu.u[0] = (g < 2) ? a0 : b0;
  pu.u[1] = (g < 2) ? a1 : b1;
  pu.u[2] = (g < 2) ? c0 : e0;
  pu.u[3] = (g < 2) ? c1 : e1;
  return pu.v;
}

static __device__ __forceinline__ void attn_tile1(const __bf16* __restrict__ Kl,
                                                  const __bf16* __restrict__ Vl,
                                                  const bf16x8* qf, f32x4* acc,
                                                  float& l_r, int j0, int q0,
                                                  bool diag, int ln15, int g) {
  f32x4 sh[4];
#pragma unroll
  for (int jt = 0; jt < 4; ++jt) sh[jt] = (f32x4){0.f, 0.f, 0.f, 0.f};
  __builtin_amdgcn_s_setprio(1);
#pragma unroll
  for (int jt = 0; jt < 4; ++jt)
#pragma unroll
    for (int kc = 0; kc < 4; ++kc) {
      int row = jt * 16 + ln15;
      int bc = (kc * 64 + g * 16) ^ ((row & 7) << 4);
      bf16x8 kf = *reinterpret_cast<const bf16x8*>(Kl + row * 128 + (bc >> 1));
      sh[jt] = MFMA_BF16(kf, qf[kc], sh[jt]);
    }
  __builtin_amdgcn_s_setprio(0);
  float p[4][4];
  softcap_p(sh, p, l_r, j0, q0, diag, ln15, g);
  int lane_lo = ln15 + 32 * (g & 1);
  int lane_hi = lane_lo + 16;
#pragma unroll
  for (int c = 0; c < 2; ++c) {
    bf16x8 pa = build_pa(p, c, lane_lo, lane_hi, g);
    __builtin_amdgcn_s_setprio(1);
#pragma unroll
    for (int d0 = 0; d0 < 8; ++d0) {
      int d = d0 * 16 + ln15;
      int bc = (c * 64 + g * 16) ^ ((d & 7) << 4);
      bf16x8 vf = *reinterpret_cast<const bf16x8*>(Vl + d * 64 + (bc >> 1));
      acc[d0] = MFMA_BF16(pa, vf, acc[d0]);
    }
    __builtin_amdgcn_s_setprio(0);
  }
}

__global__ __launch_bounds__(256, 4) void attn_kernel(const __bf16* __restrict__ qb,
                                                      const __bf16* __restrict__ kb,
                                                      const __bf16* __restrict__ vtb,
                                                      const float* __restrict__ gates,
                                                      __bf16* __restrict__ og) {
  __shared__ __align__(1024) __bf16 Kl[64 * 128];
  __shared__ __align__(1024) __bf16 Vl[128 * 64];
  int tid = threadIdx.x;
  int w = tid >> 6, lane = tid & 63;
  int ln15 = lane & 15, g = lane >> 4;
  int bx = blockIdx.x;
  int qt = 31 - (bx & 31);  // heavy blocks dispatch first
  int bh = bx >> 5;
  const __bf16* qh = qb + (size_t)bh * NSEQ * NDH;
  const __bf16* kh = kb + (size_t)bh * NSEQ * NDH;
  const __bf16* vh = vtb + (size_t)bh * NDH * NSEQ;

  int q0 = qt * 64 + w * 16;
  bf16x8 qf[4];
#pragma unroll
  for (int kc = 0; kc < 4; ++kc)
    qf[kc] = *reinterpret_cast<const bf16x8*>(qh + (size_t)(q0 + ln15) * NDH + kc * 32 + g * 8);

  f32x4 acc[8];
#pragma unroll
  for (int d0 = 0; d0 < 8; ++d0) acc[d0] = (f32x4){0.f, 0.f, 0.f, 0.f};
  float l_r = 0.f;

  auto stage = [&](int t) {
    int j0 = t * 64;
#pragma unroll
    for (int i = 0; i < 4; ++i) {
      int gi = (i * 4 + w) * 64 + lane;
      int kr = gi >> 4, kcs = gi & 15;
      int kc_ = kcs ^ (kr & 7);
      gload_lds16(kh + (size_t)(j0 + kr) * NDH + kc_ * 8, &Kl[(i * 4 + w) * 512]);
      int vr = gi >> 3, vcs = gi & 7;
      int vc_ = vcs ^ (vr & 7);
      gload_lds16(vh + (size_t)vr * NSEQ + j0 + vc_ * 8, &Vl[(i * 4 + w) * 512]);
    }
  };

  for (int t = 0; t <= qt; ++t) {
    __builtin_amdgcn_s_barrier();  // all waves done reading previous tile
    stage(t);
    asm volatile("s_waitcnt vmcnt(0)" ::: "memory");
    __builtin_amdgcn_s_barrier();  // tile t landed for all waves
    attn_tile1(Kl, Vl, qf, acc, l_r, t * 64, q0, t == qt, ln15, g);
  }

  l_r += __shfl_xor(l_r, 16);
  l_r += __shfl_xor(l_r, 32);

  int b = bh >> 4, h = bh & 15;
  float gv[4];
#pragma unroll
  for (int r = 0; r < 4; ++r) {
    float lv = __shfl(l_r, g * 4 + r);
    int row = q0 + g * 4 + r;
    gv[r] = gates[(size_t)bh * NSEQ + row] / lv;
  }
#pragma unroll
  for (int d0 = 0; d0 < 8; ++d0)
#pragma unroll
    for (int r = 0; r < 4; ++r) {
      int row = q0 + g * 4 + r;
      og[((size_t)(b * NSEQ + row)) * NDIM + h * NDH + d0 * 16 + ln15] =
          (__bf16)(acc[d0][r] * gv[r]);
    }
}

// ---------------------------------------------------------------------------
extern "C" void kernel_launch(void* const* d_in, const int* in_sizes, int n_in,
                              void* d_out, int out_size, void* d_ws, size_t ws_size,
                              hipStream_t stream) {
  const float* x = (const float*)d_in[0];
  const float* w_qkv = (const float*)d_in[1];
  const float* w_gates = (const float*)d_in[2];
  const float* w_out = (const float*)d_in[3];
  float* out = (float*)d_out;
  char* ws = (char*)d_ws;

  __bf16* x_bf   = (__bf16*)(ws + 0);          // 16,777,216
  __bf16* wqkv_t = (__bf16*)(ws + 16777216);   // 25,165,824
  __bf16* wout_t = (__bf16*)(ws + 41943040);   // 8,388,608
  __bf16* q_buf  = (__bf16*)(ws + 50331648);   // 16,777,216
  __bf16* k_buf  = (__bf16*)(ws + 67108864);   // 16,777,216
  __bf16* vt_buf = (__bf16*)(ws + 83886080);   // 16,777,216
  float*  gates  = (float*)(ws + 100663296);   // 262,144
  __bf16* attn_g = (__bf16*)(ws + 100925440);  // 16,777,216

  cvt_bf16_kernel<<<8192, 256, 0, stream>>>(x, x_bf);
  transpose_cvt_kernel<<<dim3(192, 64), 256, 0, stream>>>(w_qkv, wqkv_t, 2048, 6144);
  transpose_cvt_kernel<<<dim3(64, 64), 256, 0, stream>>>(w_out, wout_t, 2048, 2048);
  gemm_qkv256b<<<256, 512, 0, stream>>>(x_bf, wqkv_t, q_buf, k_buf, vt_buf);
  gates_kernel<<<4096, 256, 0, stream>>>(x, w_gates, gates);
  attn_kernel<<<1024, 256, 0, stream>>>(q_buf, k_buf, vt_buf, gates, attn_g);
  gemm_out128<<<256, 512, 0, stream>>>(attn_g, wout_t, out);
}